// Round 1
// baseline (557.571 us; speedup 1.0000x reference)
//
#include <hip/hip_runtime.h>

#define NTOK 64
#define DIM 192
#define HEADS 6
#define HD 32
#define SCALE 0.17677669529663687f  // 32^-0.5

typedef __bf16 bf16x8 __attribute__((ext_vector_type(8)));
typedef float f32x4 __attribute__((ext_vector_type(4)));

__device__ __forceinline__ unsigned short f2bf(float f) {
  union { float f; unsigned u; } v; v.f = f;
  unsigned u = v.u;
  return (unsigned short)((u + 0x7FFFu + ((u >> 16) & 1u)) >> 16);
}

// ---------------- pre-pass: weights -> bf16, bias gather -> dense ----------
__global__ void prep_kernel(const float* __restrict__ qkv_w,
                            const float* __restrict__ proj_w,
                            const float* __restrict__ bias_table,
                            const int* __restrict__ rel_idx,
                            unsigned short* __restrict__ wq,
                            unsigned short* __restrict__ wp,
                            float* __restrict__ biasf) {
  int i = blockIdx.x * 256 + threadIdx.x;
  if (i < 3 * DIM * DIM) wq[i] = f2bf(qkv_w[i]);
  if (i < DIM * DIM) wp[i] = f2bf(proj_w[i]);
  if (i < HEADS * NTOK * NTOK) {
    int h = i >> 12;       // 4096 entries per head
    int nm = i & 4095;
    biasf[i] = bias_table[rel_idx[nm] * HEADS + h];
  }
}

// ---------------- fused window attention: 1 block = 1 window ----------------
__global__ __launch_bounds__(384) void attn_kernel(
    const float* __restrict__ x,
    const float* __restrict__ qkv_b,
    const float* __restrict__ proj_b,
    const unsigned short* __restrict__ wq,
    const unsigned short* __restrict__ wp,
    const float* __restrict__ biasf,
    float* __restrict__ out) {
  // xs: x as bf16, row stride 200 (pad +8 -> even bank spread); reused as
  // attention-output (proj A operand) after stage 3.
  __shared__ unsigned short xs[NTOK * 200];        // 25600 B
  __shared__ unsigned short qs[HEADS * NTOK * HD]; // 24576 B  q (pre-scaled)
  __shared__ unsigned short kk[HEADS * NTOK * HD]; // 24576 B  k
  __shared__ unsigned short vts[HEADS * HD * 72];  // 27648 B  v^T [h][d][m]
  __shared__ unsigned short Ps[HEADS * NTOK * 72]; // 55296 B  P  [h][n][m]

  const int tid = threadIdx.x;
  const int w = tid >> 6;       // wave 0..5
  const int lane = tid & 63;
  const int l15 = lane & 15;
  const int quad = lane >> 4;
  const long b = blockIdx.x;

  // ---- stage 1: load x (fp32) -> LDS bf16 ----
  {
    const float4* xg = (const float4*)(x + b * (NTOK * DIM));
    #pragma unroll
    for (int it = 0; it < 8; ++it) {
      int idx = tid + it * 384;        // 3072 float4 total
      float4 v = xg[idx];
      int row = idx / 48;
      int col = (idx % 48) * 4;
      ushort4 o;
      o.x = f2bf(v.x); o.y = f2bf(v.y); o.z = f2bf(v.z); o.w = f2bf(v.w);
      *(ushort4*)&xs[row * 200 + col] = o;
    }
  }
  __syncthreads();

  // ---- stage 2: QKV GEMM  qkv[n][j] = sum_c x[n][c] * Wq[j][c] + b[j] ----
  for (int i = 0; i < 6; ++i) {
    int jt = w * 6 + i;            // col tile 0..35
    int j = jt * 16 + l15;         // output col in [0,576)
    f32x4 acc[4] = {f32x4{0.f,0.f,0.f,0.f}, f32x4{0.f,0.f,0.f,0.f},
                    f32x4{0.f,0.f,0.f,0.f}, f32x4{0.f,0.f,0.f,0.f}};
    #pragma unroll
    for (int ks = 0; ks < 6; ++ks) {
      bf16x8 bw = *(const bf16x8*)(wq + (size_t)j * DIM + ks * 32 + quad * 8);
      #pragma unroll
      for (int rt = 0; rt < 4; ++rt) {
        bf16x8 a = *(const bf16x8*)&xs[(rt * 16 + l15) * 200 + ks * 32 + quad * 8];
        acc[rt] = __builtin_amdgcn_mfma_f32_16x16x32_bf16(a, bw, acc[rt], 0, 0, 0);
      }
    }
    float bj = qkv_b[j];
    int which = jt / 12;           // 0=q 1=k 2=v
    int ft = jt % 12;
    int h = ft >> 1;
    int d = (ft & 1) * 16 + l15;
    if (which == 0) {
      #pragma unroll
      for (int rt = 0; rt < 4; ++rt)
        #pragma unroll
        for (int g = 0; g < 4; ++g) {
          int row = rt * 16 + quad * 4 + g;
          qs[(h * NTOK + row) * HD + d] = f2bf((acc[rt][g] + bj) * SCALE);
        }
    } else if (which == 1) {
      #pragma unroll
      for (int rt = 0; rt < 4; ++rt)
        #pragma unroll
        for (int g = 0; g < 4; ++g) {
          int row = rt * 16 + quad * 4 + g;
          kk[(h * NTOK + row) * HD + d] = f2bf(acc[rt][g] + bj);
        }
    } else {
      #pragma unroll
      for (int rt = 0; rt < 4; ++rt) {
        ushort4 o;
        o.x = f2bf(acc[rt][0] + bj);
        o.y = f2bf(acc[rt][1] + bj);
        o.z = f2bf(acc[rt][2] + bj);
        o.w = f2bf(acc[rt][3] + bj);
        int row0 = rt * 16 + quad * 4;
        *(ushort4*)&vts[(h * HD + d) * 72 + row0] = o;
      }
    }
  }
  __syncthreads();

  // ---- stage 3: attention, wave w = head w ----
  {
    const int h = w;
    bf16x8 qa[4], kb[4];
    #pragma unroll
    for (int rt = 0; rt < 4; ++rt)
      qa[rt] = *(const bf16x8*)&qs[(h * NTOK + rt * 16 + l15) * HD + quad * 8];
    #pragma unroll
    for (int ct = 0; ct < 4; ++ct)
      kb[ct] = *(const bf16x8*)&kk[(h * NTOK + ct * 16 + l15) * HD + quad * 8];
    f32x4 s[4][4];
    #pragma unroll
    for (int rt = 0; rt < 4; ++rt)
      #pragma unroll
      for (int ct = 0; ct < 4; ++ct) {
        s[rt][ct] = f32x4{0.f, 0.f, 0.f, 0.f};
        s[rt][ct] = __builtin_amdgcn_mfma_f32_16x16x32_bf16(qa[rt], kb[ct], s[rt][ct], 0, 0, 0);
      }
    // softmax over m (cols); row r's 64 values live on the 16 lanes of this
    // quad's lane15 group x 4 col-tiles -> register+shfl reduction.
    const float* bh = biasf + h * 4096;
    #pragma unroll
    for (int rt = 0; rt < 4; ++rt) {
      #pragma unroll
      for (int g = 0; g < 4; ++g) {
        int row = rt * 16 + quad * 4 + g;
        const float* bp = bh + row * 64 + l15;
        float v0 = s[rt][0][g] + bp[0];
        float v1 = s[rt][1][g] + bp[16];
        float v2 = s[rt][2][g] + bp[32];
        float v3 = s[rt][3][g] + bp[48];
        float mx = fmaxf(fmaxf(v0, v1), fmaxf(v2, v3));
        mx = fmaxf(mx, __shfl_xor(mx, 1));
        mx = fmaxf(mx, __shfl_xor(mx, 2));
        mx = fmaxf(mx, __shfl_xor(mx, 4));
        mx = fmaxf(mx, __shfl_xor(mx, 8));
        float e0 = __expf(v0 - mx);
        float e1 = __expf(v1 - mx);
        float e2 = __expf(v2 - mx);
        float e3 = __expf(v3 - mx);
        float sm = e0 + e1 + e2 + e3;
        sm += __shfl_xor(sm, 1);
        sm += __shfl_xor(sm, 2);
        sm += __shfl_xor(sm, 4);
        sm += __shfl_xor(sm, 8);
        float r = __builtin_amdgcn_rcpf(sm);
        int base = (h * NTOK + row) * 72 + l15;
        Ps[base + 0]  = f2bf(e0 * r);
        Ps[base + 16] = f2bf(e1 * r);
        Ps[base + 32] = f2bf(e2 * r);
        Ps[base + 48] = f2bf(e3 * r);
      }
    }
    // PV: out[n][d] = sum_m P[n][m] v[m][d]; B operand from v^T (m-contig)
    bf16x8 vb[2][2];
    #pragma unroll
    for (int c2 = 0; c2 < 2; ++c2)
      #pragma unroll
      for (int kv = 0; kv < 2; ++kv)
        vb[c2][kv] = *(const bf16x8*)&vts[(h * HD + c2 * 16 + l15) * 72 + kv * 32 + quad * 8];
    f32x4 o[4][2];
    #pragma unroll
    for (int rt = 0; rt < 4; ++rt)
      #pragma unroll
      for (int c2 = 0; c2 < 2; ++c2)
        o[rt][c2] = f32x4{0.f, 0.f, 0.f, 0.f};
    #pragma unroll
    for (int rt = 0; rt < 4; ++rt)
      #pragma unroll
      for (int kv = 0; kv < 2; ++kv) {
        bf16x8 pa = *(const bf16x8*)&Ps[(h * NTOK + rt * 16 + l15) * 72 + kv * 32 + quad * 8];
        #pragma unroll
        for (int c2 = 0; c2 < 2; ++c2)
          o[rt][c2] = __builtin_amdgcn_mfma_f32_16x16x32_bf16(pa, vb[c2][kv], o[rt][c2], 0, 0, 0);
      }
    // write attention output (bf16) into xs (reused) as proj A operand
    #pragma unroll
    for (int rt = 0; rt < 4; ++rt)
      #pragma unroll
      for (int c2 = 0; c2 < 2; ++c2)
        #pragma unroll
        for (int g = 0; g < 4; ++g) {
          int row = rt * 16 + quad * 4 + g;
          xs[row * 200 + h * HD + c2 * 16 + l15] = f2bf(o[rt][c2][g]);
        }
  }
  __syncthreads();

  // ---- stage 4: proj GEMM  out[n][e] = sum_f a[n][f] Wp[e][f] + pb[e] ----
  for (int i = 0; i < 2; ++i) {
    int et = w * 2 + i;            // col tile 0..11
    int e = et * 16 + l15;
    f32x4 acc[4] = {f32x4{0.f,0.f,0.f,0.f}, f32x4{0.f,0.f,0.f,0.f},
                    f32x4{0.f,0.f,0.f,0.f}, f32x4{0.f,0.f,0.f,0.f}};
    #pragma unroll
    for (int ks = 0; ks < 6; ++ks) {
      bf16x8 bw = *(const bf16x8*)(wp + (size_t)e * DIM + ks * 32 + quad * 8);
      #pragma unroll
      for (int rt = 0; rt < 4; ++rt) {
        bf16x8 a = *(const bf16x8*)&xs[(rt * 16 + l15) * 200 + ks * 32 + quad * 8];
        acc[rt] = __builtin_amdgcn_mfma_f32_16x16x32_bf16(a, bw, acc[rt], 0, 0, 0);
      }
    }
    float pb = proj_b[e];
    float* og = out + b * (NTOK * DIM);
    #pragma unroll
    for (int rt = 0; rt < 4; ++rt)
      #pragma unroll
      for (int g = 0; g < 4; ++g) {
        int row = rt * 16 + quad * 4 + g;
        og[row * DIM + e] = acc[rt][g] + pb;
      }
  }
}

extern "C" void kernel_launch(void* const* d_in, const int* in_sizes, int n_in,
                              void* d_out, int out_size, void* d_ws, size_t ws_size,
                              hipStream_t stream) {
  const float* x          = (const float*)d_in[0];
  const float* qkv_w      = (const float*)d_in[1];
  const float* qkv_b      = (const float*)d_in[2];
  const float* proj_w     = (const float*)d_in[3];
  const float* proj_b     = (const float*)d_in[4];
  const float* bias_table = (const float*)d_in[5];
  const int*   rel_idx    = (const int*)d_in[6];

  unsigned short* wq = (unsigned short*)d_ws;            // 110592 bf16
  unsigned short* wp = wq + 3 * DIM * DIM;               // 36864 bf16
  float* biasf = (float*)(wp + DIM * DIM);               // 24576 fp32 (byte 294912)

  prep_kernel<<<432, 256, 0, stream>>>(qkv_w, proj_w, bias_table, rel_idx, wq, wp, biasf);
  attn_kernel<<<4096, 384, 0, stream>>>(x, qkv_b, proj_b, wq, wp, biasf, (float*)d_out);
}